// Round 8
// baseline (147.063 us; speedup 1.0000x reference)
//
#include <hip/hip_runtime.h>
#include <hip/hip_fp16.h>

// msg[e] = src_emb[src_idx[e]] * e_att[e]; out = segment_sum(msg, dst_idx, N_DST)
// src_emb [50000,64] f32, e_att [800000,1] f32, src_idx/dst_idx [800000] i32,
// out [50000,64] f32.
//
// R8 pipeline:
//   convert: src_emb f32 -> f16 (6.4 MB)
//   stage1:  single-pass 8-way binning; LDS-staged contiguous runs -> per
//            -partition compacted record lists (8B records, coalesced writes)
//   stage2:  per-partition scatter (blockIdx&7 = partition = XCD affinity):
//            stream records, cursor atomic, 4B payload into L2-resident
//            bucket region (partition p owns rows w == p mod 8)
//   gather:  one wave per dst row (partition-swizzled), preload 256B bucket,
//            readlane (src,att16) -> 128B f16 row loads, 4x unrolled fma.
// No global atomics on the output path; overflow paths are insurance only.

#define D 64
#define CAP 64              // payload slots per dst bucket (deg mean 16, max ~45)
#define OVF_CAP 65536
#define NPART 8
#define SCAP 512            // LDS staging slots per partition per block

// ---------------- convert: f32 -> f16 ----------------
__global__ void __launch_bounds__(256)
convert_emb_kernel(const float* __restrict__ src, __half* __restrict__ dst, int n4) {
    int i = blockIdx.x * blockDim.x + threadIdx.x;
    if (i >= n4) return;
    float4 v = ((const float4*)src)[i];
    ushort4 h;
    h.x = __half_as_ushort(__float2half(v.x));
    h.y = __half_as_ushort(__float2half(v.y));
    h.z = __half_as_ushort(__float2half(v.z));
    h.w = __half_as_ushort(__float2half(v.w));
    ((ushort4*)dst)[i] = h;
}

// ---------------- stage 1: 8-way binning with LDS staging ----------------
// record (8B): lo32 = src16 | (dlocal13 << 16), hi32 = att16
__global__ void __launch_bounds__(256)
bin8_kernel(const int* __restrict__ dst_idx, const int* __restrict__ src_idx,
            const float* __restrict__ e_att,
            unsigned long long* __restrict__ plist, int* __restrict__ gcur8,
            int E, int pcap, int epb) {
    __shared__ unsigned long long stage[NPART * SCAP];   // 32 KB
    __shared__ int cnt[NPART];
    __shared__ int base_[NPART];
    int t = threadIdx.x;
    if (t < NPART) cnt[t] = 0;
    __syncthreads();

    int e0 = blockIdx.x * epb;
    int e1 = min(e0 + epb, E);
    for (int e = e0 + t; e < e1; e += 256) {
        int d = dst_idx[e];
        int p = d & (NPART - 1);
        unsigned dl = (unsigned)d >> 3;
        unsigned short a16 = __half_as_ushort(__float2half(e_att[e]));
        unsigned long long rec = (unsigned long long)a16 << 32 |
                                 ((unsigned)src_idx[e] | (dl << 16));
        int slot = atomicAdd(&cnt[p], 1);
        if (slot < SCAP) {
            stage[p * SCAP + slot] = rec;
        } else {                                   // rare LDS overflow: direct append
            int g = atomicAdd(&gcur8[p], 1);
            if (g < pcap) plist[(size_t)p * pcap + g] = rec;
        }
    }
    __syncthreads();
    if (t < NPART) base_[t] = atomicAdd(&gcur8[t], min(cnt[t], SCAP));
    __syncthreads();
    for (int p = 0; p < NPART; ++p) {
        int n = min(cnt[p], SCAP);
        unsigned long long* dstp = plist + (size_t)p * pcap + base_[p];
        for (int i = t; i < n; i += 256)
            __builtin_nontemporal_store(stage[p * SCAP + i], dstp + i);
    }
}

// ---------------- stage 2: per-partition scatter ----------------
__global__ void __launch_bounds__(256)
scatter2_kernel(const unsigned long long* __restrict__ plist,
                const int* __restrict__ gcur8, int* __restrict__ cursor,
                unsigned* __restrict__ payload,
                int* __restrict__ ovf_count, unsigned long long* __restrict__ ovf_list,
                int pcap, int cpp) {
    int p     = blockIdx.x & (NPART - 1);       // partition == XCD affinity
    int chunk = blockIdx.x >> 3;
    int len   = gcur8[p];
    const unsigned long long* lp = plist + (size_t)p * pcap;
    int stride = cpp * 256;
    for (int i = chunk * 256 + threadIdx.x; i < len; i += stride) {
        unsigned long long rec = lp[i];
        unsigned lo  = (unsigned)rec;
        unsigned a16 = (unsigned)(rec >> 32) & 0xffffu;
        unsigned src = lo & 0xffffu;
        unsigned dl  = lo >> 16;
        int d = (int)((dl << 3) | (unsigned)p);
        int slot = atomicAdd(&cursor[d], 1);
        unsigned pay = (a16 << 16) | src;
        if (slot < CAP) {
            payload[(size_t)d * CAP + slot] = pay;   // L2-resident region
        } else {
            int oi = atomicAdd(ovf_count, 1);
            if (oi < OVF_CAP)
                ovf_list[oi] = ((unsigned long long)(unsigned)d << 32) | pay;
        }
    }
}

// ---------------- gather: one wave per dst row ----------------
__global__ void __launch_bounds__(256)
gather_kernel(const __half* __restrict__ emb_h,
              const unsigned* __restrict__ payload,
              const int* __restrict__ cursor,
              const int* __restrict__ ovf_count,
              const unsigned long long* __restrict__ ovf_list,
              float* __restrict__ out, int n_dst, int rpx) {
    int p    = blockIdx.x & (NPART - 1);
    int g    = blockIdx.x >> 3;
    int wv   = threadIdx.x >> 6;
    int lane = threadIdx.x & 63;
    int local = g * 4 + wv;
    if (local >= rpx) return;
    int w = (local << 3) | p;                   // dst row; partition p = w&7
    if (w >= n_dst) return;

    int cn  = cursor[w];
    int cnt = min(cn, CAP);

    unsigned plv = payload[(size_t)w * CAP + lane];   // 256B coalesced preload
    int pli = (int)plv;

    float acc = 0.f;
    int j = 0;
    for (; j + 4 <= cnt; j += 4) {
        unsigned p0 = (unsigned)__builtin_amdgcn_readlane(pli, j);
        unsigned p1 = (unsigned)__builtin_amdgcn_readlane(pli, j + 1);
        unsigned p2 = (unsigned)__builtin_amdgcn_readlane(pli, j + 2);
        unsigned p3 = (unsigned)__builtin_amdgcn_readlane(pli, j + 3);
        float a0 = __half2float(__ushort_as_half((unsigned short)(p0 >> 16)));
        float a1 = __half2float(__ushort_as_half((unsigned short)(p1 >> 16)));
        float a2 = __half2float(__ushort_as_half((unsigned short)(p2 >> 16)));
        float a3 = __half2float(__ushort_as_half((unsigned short)(p3 >> 16)));
        float v0 = __half2float(emb_h[(size_t)(p0 & 0xffff) * D + lane]);
        float v1 = __half2float(emb_h[(size_t)(p1 & 0xffff) * D + lane]);
        float v2 = __half2float(emb_h[(size_t)(p2 & 0xffff) * D + lane]);
        float v3 = __half2float(emb_h[(size_t)(p3 & 0xffff) * D + lane]);
        acc = fmaf(v0, a0, acc);
        acc = fmaf(v1, a1, acc);
        acc = fmaf(v2, a2, acc);
        acc = fmaf(v3, a3, acc);
    }
    for (; j < cnt; ++j) {
        unsigned pv = (unsigned)__builtin_amdgcn_readlane(pli, j);
        float a = __half2float(__ushort_as_half((unsigned short)(pv >> 16)));
        acc = fmaf(__half2float(emb_h[(size_t)(pv & 0xffff) * D + lane]), a, acc);
    }

    if (cn > CAP) {                              // insurance (expected never)
        int oc = min(*ovf_count, OVF_CAP);
        for (int i = 0; i < oc; ++i) {
            unsigned long long orec = ovf_list[i];
            if ((int)(orec >> 32) == w) {
                unsigned pv = (unsigned)orec;
                float a = __half2float(__ushort_as_half((unsigned short)(pv >> 16)));
                acc = fmaf(__half2float(emb_h[(size_t)(pv & 0xffff) * D + lane]), a, acc);
            }
        }
    }
    out[(size_t)w * D + lane] = acc;             // contiguous 256B row store
}

// ---------------- fallback: pure atomic ----------------
__global__ void __launch_bounds__(256)
atomic_fallback_kernel(const float* __restrict__ src_emb, const float* __restrict__ e_att,
                       const int* __restrict__ src_idx, const int* __restrict__ dst_idx,
                       float* __restrict__ out, int E) {
    int tid  = blockIdx.x * blockDim.x + threadIdx.x;
    int e    = tid >> 4;
    int part = tid & 15;
    if (e >= E) return;
    int   s = src_idx[e];
    int   d = dst_idx[e];
    float a = e_att[e];
    float4 v = ((const float4*)src_emb)[(size_t)s * 16 + part];
    float* orow = out + (size_t)d * D + part * 4;
    atomicAdd(orow + 0, v.x * a);
    atomicAdd(orow + 1, v.y * a);
    atomicAdd(orow + 2, v.z * a);
    atomicAdd(orow + 3, v.w * a);
}

extern "C" void kernel_launch(void* const* d_in, const int* in_sizes, int n_in,
                              void* d_out, int out_size, void* d_ws, size_t ws_size,
                              hipStream_t stream) {
    const float* src_emb = (const float*)d_in[0];
    const float* e_att   = (const float*)d_in[1];
    const int*   src_idx = (const int*)d_in[2];
    const int*   dst_idx = (const int*)d_in[3];
    float*       out     = (float*)d_out;

    const int E     = in_sizes[2];       // 800000
    const int n_dst = out_size / D;      // 50000
    const int n_src = in_sizes[0] / D;   // 50000
    const int rpx   = (n_dst + NPART - 1) / NPART;   // rows per partition (6250)
    const int pcap  = E;                 // per-partition list capacity (no overflow possible)

    // ws layout (bytes, 8B-aligned segments first):
    //   plist[NPART*pcap] ull | ovf_list[OVF_CAP] ull | emb_h[n_src*D] half |
    //   payload[n_dst*CAP] u32 | cursor[n_dst] | gcur8[8] | ovf_count[1]
    size_t off_plist = 0;
    size_t off_ovf   = off_plist + (size_t)NPART * pcap * 8;
    size_t off_emb   = off_ovf + (size_t)OVF_CAP * 8;
    size_t off_pay   = off_emb + (size_t)n_src * D * 2;
    size_t off_cur   = off_pay + (size_t)n_dst * CAP * 4;
    size_t need      = off_cur + ((size_t)n_dst + NPART + 1) * 4;

    if (n_src <= 65536 && rpx <= 8192 && ws_size >= need) {
        char* ws = (char*)d_ws;
        unsigned long long* plist    = (unsigned long long*)(ws + off_plist);
        unsigned long long* ovf_list = (unsigned long long*)(ws + off_ovf);
        __half*   emb_h   = (__half*)(ws + off_emb);
        unsigned* payload = (unsigned*)(ws + off_pay);
        int*      cursor  = (int*)(ws + off_cur);
        int*      gcur8   = cursor + n_dst;
        int*      ovf_count = gcur8 + NPART;

        // zero cursor + gcur8 + ovf_count in one memset
        hipMemsetAsync(cursor, 0, ((size_t)n_dst + NPART + 1) * sizeof(int), stream);

        convert_emb_kernel<<<(n_src * D / 4 + 255) / 256, 256, 0, stream>>>(
            src_emb, emb_h, n_src * D / 4);

        const int s1_blocks = 256;
        const int epb = (E + s1_blocks - 1) / s1_blocks;   // 3125
        bin8_kernel<<<s1_blocks, 256, 0, stream>>>(dst_idx, src_idx, e_att,
                                                   plist, gcur8, E, pcap, epb);

        const int cpp = 64;                                 // chunks per partition
        scatter2_kernel<<<cpp * NPART, 256, 0, stream>>>(plist, gcur8, cursor,
                                                         payload, ovf_count,
                                                         ovf_list, pcap, cpp);

        const int gpb = (rpx + 3) / 4;                      // gather blocks/partition
        gather_kernel<<<gpb * NPART, 256, 0, stream>>>(emb_h, payload, cursor,
                                                       ovf_count, ovf_list,
                                                       out, n_dst, rpx);
        return;
    }

    // fallback: pure atomic
    hipMemsetAsync(d_out, 0, (size_t)out_size * sizeof(float), stream);
    atomic_fallback_kernel<<<(E * 16 + 255) / 256, 256, 0, stream>>>(
        src_emb, e_att, src_idx, dst_idx, out, E);
}

// Round 9
// 134.905 us; speedup vs baseline: 1.0901x; 1.0901x over previous
//
#include <hip/hip_runtime.h>
#include <hip/hip_fp16.h>

// msg[e] = src_emb[src_idx[e]] * e_att[e]; out = segment_sum(msg, dst_idx, N_DST)
// src_emb [50000,64] f32, e_att [800000,1] f32, src_idx/dst_idx [800000] i32,
// out [50000,64] f32.
//
// R9 = R7 (best scatter) + fp16-emb gather (validated in R8: absmax 0.0625).
//   convert: src_emb f32 -> f16 (also zeroes cursor; kills memset dispatch)
//   scatter: XCD-partitioned padded buckets — block b handles dst range of
//            partition (b&7); 8x edge rescan (L3-absorbed) so each partition's
//            1.6 MB bucket region is written while L2-resident.
//   gather:  one wave per dst row (same partition swizzle), preload 256B
//            bucket, readlane (src16,att16) -> 128B fp16 row loads, 4x unroll.
// No global atomics on the output path; overflow insurance only.

#define D 64
#define CAP 64              // slots per dst bucket; deg ~ Binom(E,1/N), max ~45
#define OVF_CAP 65536
#define NPART 8

// ---------------- convert f32->f16 + zero cursor ----------------
__global__ void __launch_bounds__(256)
convert_emb_kernel(const float* __restrict__ src, __half* __restrict__ dst, int n4,
                   int* __restrict__ cursor, int ncur) {
    int i = blockIdx.x * blockDim.x + threadIdx.x;
    if (i < ncur) cursor[i] = 0;                 // cursor[n_dst] + ovf_count
    if (i >= n4) return;
    float4 v = ((const float4*)src)[i];
    ushort4 h;
    h.x = __half_as_ushort(__float2half(v.x));
    h.y = __half_as_ushort(__float2half(v.y));
    h.z = __half_as_ushort(__float2half(v.z));
    h.w = __half_as_ushort(__float2half(v.w));
    ((ushort4*)dst)[i] = h;
}

// ---------------- scatter (R7) ----------------
__global__ void __launch_bounds__(256)
scatter_xcd_kernel(const int* __restrict__ dst_idx, const int* __restrict__ src_idx,
                   const float* __restrict__ e_att, int* __restrict__ cursor,
                   unsigned* __restrict__ payload,
                   int* __restrict__ ovf_count, int* __restrict__ ovf_list,
                   int E, int n_dst, int rpx, int epb) {
    int x     = blockIdx.x & (NPART - 1);   // dst partition == target XCD
    int chunk = blockIdx.x >> 3;
    int e0 = chunk * epb;
    int e1 = min(e0 + epb, E);
    int lo = x * rpx;
    int hi = min(lo + rpx, n_dst);

    for (int e = e0 + threadIdx.x; e < e1; e += 256) {
        int d = dst_idx[e];
        if (d < lo || d >= hi) continue;
        int p = atomicAdd(&cursor[d], 1);
        if (p < CAP) {
            unsigned pl = (unsigned)src_idx[e] |
                          ((unsigned)__half_as_ushort(__float2half(e_att[e])) << 16);
            payload[(size_t)d * CAP + p] = pl;      // L2-local on owning XCD
        } else {
            int oi = atomicAdd(ovf_count, 1);
            if (oi < OVF_CAP) ovf_list[oi] = e;
        }
    }
}

// ---------------- gather: one wave per dst row ----------------
__global__ void __launch_bounds__(256)
gather_xcd_kernel(const __half* __restrict__ emb_h,
                  const unsigned* __restrict__ payload,
                  const int* __restrict__ cursor,
                  const int* __restrict__ dst_idx, const int* __restrict__ src_idx,
                  const float* __restrict__ e_att, const float* __restrict__ src_emb,
                  const int* __restrict__ ovf_count, const int* __restrict__ ovf_list,
                  float* __restrict__ out, int n_dst, int rpx) {
    int x    = blockIdx.x & (NPART - 1);
    int g    = blockIdx.x >> 3;
    int wv   = threadIdx.x >> 6;
    int lane = threadIdx.x & 63;
    int local = g * 4 + wv;
    if (local >= rpx) return;
    int w = x * rpx + local;                // dst row (bucket)
    if (w >= n_dst) return;

    int cn  = cursor[w];
    int cnt = min(cn, CAP);

    // one coalesced 256B read: lane l holds payload slot l
    unsigned plv = payload[(size_t)w * CAP + lane];
    int pli = (int)plv;

    float acc = 0.f;
    int j = 0;
    for (; j + 4 <= cnt; j += 4) {
        unsigned p0 = (unsigned)__builtin_amdgcn_readlane(pli, j);
        unsigned p1 = (unsigned)__builtin_amdgcn_readlane(pli, j + 1);
        unsigned p2 = (unsigned)__builtin_amdgcn_readlane(pli, j + 2);
        unsigned p3 = (unsigned)__builtin_amdgcn_readlane(pli, j + 3);
        float a0 = __half2float(__ushort_as_half((unsigned short)(p0 >> 16)));
        float a1 = __half2float(__ushort_as_half((unsigned short)(p1 >> 16)));
        float a2 = __half2float(__ushort_as_half((unsigned short)(p2 >> 16)));
        float a3 = __half2float(__ushort_as_half((unsigned short)(p3 >> 16)));
        // 4 independent 128B fp16 row reads in flight
        float v0 = __half2float(emb_h[(size_t)(p0 & 0xffff) * D + lane]);
        float v1 = __half2float(emb_h[(size_t)(p1 & 0xffff) * D + lane]);
        float v2 = __half2float(emb_h[(size_t)(p2 & 0xffff) * D + lane]);
        float v3 = __half2float(emb_h[(size_t)(p3 & 0xffff) * D + lane]);
        acc = fmaf(v0, a0, acc);
        acc = fmaf(v1, a1, acc);
        acc = fmaf(v2, a2, acc);
        acc = fmaf(v3, a3, acc);
    }
    for (; j < cnt; ++j) {
        unsigned pv = (unsigned)__builtin_amdgcn_readlane(pli, j);
        float a = __half2float(__ushort_as_half((unsigned short)(pv >> 16)));
        acc = fmaf(__half2float(emb_h[(size_t)(pv & 0xffff) * D + lane]), a, acc);
    }

    // insurance: bucket overflow (expected never). Exact f32 path.
    if (cn > CAP) {
        int oc = *ovf_count;
        if (oc > OVF_CAP) oc = OVF_CAP;
        for (int i = 0; i < oc; ++i) {
            int e = ovf_list[i];
            if (dst_idx[e] == w) {
                float a = e_att[e];
                int   s = src_idx[e];
                acc = fmaf(src_emb[(size_t)s * D + lane], a, acc);
            }
        }
    }

    out[(size_t)w * D + lane] = acc;        // contiguous 256B row store
}

// ---------------- fallback: pure atomic ----------------
__global__ void __launch_bounds__(256)
atomic_fallback_kernel(const float* __restrict__ src_emb, const float* __restrict__ e_att,
                       const int* __restrict__ src_idx, const int* __restrict__ dst_idx,
                       float* __restrict__ out, int E) {
    int tid  = blockIdx.x * blockDim.x + threadIdx.x;
    int e    = tid >> 4;
    int part = tid & 15;
    if (e >= E) return;
    int   s = src_idx[e];
    int   d = dst_idx[e];
    float a = e_att[e];
    float4 v = ((const float4*)src_emb)[(size_t)s * 16 + part];
    float* orow = out + (size_t)d * D + part * 4;
    atomicAdd(orow + 0, v.x * a);
    atomicAdd(orow + 1, v.y * a);
    atomicAdd(orow + 2, v.z * a);
    atomicAdd(orow + 3, v.w * a);
}

extern "C" void kernel_launch(void* const* d_in, const int* in_sizes, int n_in,
                              void* d_out, int out_size, void* d_ws, size_t ws_size,
                              hipStream_t stream) {
    const float* src_emb = (const float*)d_in[0];
    const float* e_att   = (const float*)d_in[1];
    const int*   src_idx = (const int*)d_in[2];
    const int*   dst_idx = (const int*)d_in[3];
    float*       out     = (float*)d_out;

    const int E     = in_sizes[2];       // 800000
    const int n_dst = out_size / D;      // 50000
    const int n_src = in_sizes[0] / D;   // 50000

    // ws layout (4B units): emb_h[n_src*D/2] | payload[n_dst*CAP] | cursor[n_dst]
    //                       | ovf_count[1] | ovf_list[OVF_CAP]
    size_t off_emb = 0;
    size_t off_pay = off_emb + (size_t)n_src * D / 2;
    size_t off_cur = off_pay + (size_t)n_dst * CAP;
    size_t need_ints = off_cur + (size_t)n_dst + 1 + OVF_CAP;

    if (n_src <= 65536 && ws_size >= need_ints * sizeof(int)) {
        __half*   emb_h   = (__half*)d_ws;
        unsigned* payload = (unsigned*)d_ws + off_pay;
        int*      cursor  = (int*)d_ws + off_cur;
        int*      ovf_count = cursor + n_dst;
        int*      ovf_list  = ovf_count + 1;

        const int n4 = n_src * D / 4;
        convert_emb_kernel<<<(n4 + 255) / 256, 256, 0, stream>>>(
            src_emb, emb_h, n4, cursor, n_dst + 1);

        const int rpx = (n_dst + NPART - 1) / NPART;   // 6250 dst rows/partition
        const int chunks = 512;
        const int epb    = (E + chunks - 1) / chunks;
        scatter_xcd_kernel<<<chunks * NPART, 256, 0, stream>>>(
            dst_idx, src_idx, e_att, cursor, payload, ovf_count, ovf_list,
            E, n_dst, rpx, epb);

        const int gpb = (rpx + 3) / 4;                 // 4 rows per block
        gather_xcd_kernel<<<gpb * NPART, 256, 0, stream>>>(
            emb_h, payload, cursor, dst_idx, src_idx, e_att, src_emb,
            ovf_count, ovf_list, out, n_dst, rpx);
        return;
    }

    // fallback: pure atomic
    hipMemsetAsync(d_out, 0, (size_t)out_size * sizeof(float), stream);
    atomic_fallback_kernel<<<(E * 16 + 255) / 256, 256, 0, stream>>>(
        src_emb, e_att, src_idx, dst_idx, out, E);
}

// Round 10
// 131.131 us; speedup vs baseline: 1.1215x; 1.0288x over previous
//
#include <hip/hip_runtime.h>
#include <hip/hip_fp16.h>

// msg[e] = src_emb[src_idx[e]] * e_att[e]; out = segment_sum(msg, dst_idx, N_DST)
// src_emb [50000,64] f32, e_att [800000,1] f32, src_idx/dst_idx [800000] i32,
// out [50000,64] f32.
//
// R10 = R9 with: (1) int4-vectorized scatter scan (4 edges/lane/iter,
// unconditional vector loads of dst/src/att), (2) dual-row gather: one wave
// covers 2 dst rows (32 lanes each), __half2 4B/lane row loads (full-dword TA
// path), payload pulled via __shfl from a uint2 preload, 4-slot unroll.
// Scatter remains XCD-partitioned (blockIdx&7 = partition; 8x rescan,
// L3-absorbed) so each partition's 1.6MB bucket region stays L2-resident.

#define D 64
#define CAP 64              // slots per dst bucket; deg ~ Binom(E,1/N), max ~45
#define OVF_CAP 65536
#define NPART 8

// ---------------- convert f32->f16 + zero cursor ----------------
__global__ void __launch_bounds__(256)
convert_emb_kernel(const float* __restrict__ src, __half* __restrict__ dst, int n4,
                   int* __restrict__ cursor, int ncur) {
    int i = blockIdx.x * blockDim.x + threadIdx.x;
    if (i < ncur) cursor[i] = 0;                 // cursor[n_dst] + ovf_count
    if (i >= n4) return;
    float4 v = ((const float4*)src)[i];
    ushort4 h;
    h.x = __half_as_ushort(__float2half(v.x));
    h.y = __half_as_ushort(__float2half(v.y));
    h.z = __half_as_ushort(__float2half(v.z));
    h.w = __half_as_ushort(__float2half(v.w));
    ((ushort4*)dst)[i] = h;
}

// ---------------- scatter: XCD-partitioned, int4-vectorized scan ----------------
__global__ void __launch_bounds__(256)
scatter_xcd_kernel(const int* __restrict__ dst_idx, const int* __restrict__ src_idx,
                   const float* __restrict__ e_att, int* __restrict__ cursor,
                   unsigned* __restrict__ payload,
                   int* __restrict__ ovf_count, int* __restrict__ ovf_list,
                   int E, int n_dst, int rpx, int epb4) {
    int x     = blockIdx.x & (NPART - 1);   // dst partition == target XCD
    int chunk = blockIdx.x >> 3;
    int lo = x * rpx;
    int hi = min(lo + rpx, n_dst);

    int E4 = E >> 2;
    int i0 = chunk * epb4;
    int i1 = min(i0 + epb4, E4);

    for (int i = i0 + threadIdx.x; i < i1; i += 256) {
        int4   d4 = ((const int4*)dst_idx)[i];
        int4   s4 = ((const int4*)src_idx)[i];
        float4 a4 = ((const float4*)e_att)[i];
        int   dd[4] = {d4.x, d4.y, d4.z, d4.w};
        int   ss[4] = {s4.x, s4.y, s4.z, s4.w};
        float aa[4] = {a4.x, a4.y, a4.z, a4.w};
#pragma unroll
        for (int k = 0; k < 4; ++k) {
            int d = dd[k];
            if (d < lo || d >= hi) continue;
            int p = atomicAdd(&cursor[d], 1);
            unsigned pay = (unsigned)ss[k] |
                           ((unsigned)__half_as_ushort(__float2half(aa[k])) << 16);
            if (p < CAP) {
                payload[(size_t)d * CAP + p] = pay;   // L2-local on owning XCD
            } else {
                int oi = atomicAdd(ovf_count, 1);
                if (oi < OVF_CAP) ovf_list[oi] = 4 * i + k;
            }
        }
    }
    // tail (E % 4 edges): chunk 0 of every partition, scalar
    if (chunk == 0) {
        for (int e = (E4 << 2) + threadIdx.x; e < E; e += 256) {
            int d = dst_idx[e];
            if (d < lo || d >= hi) continue;
            int p = atomicAdd(&cursor[d], 1);
            unsigned pay = (unsigned)src_idx[e] |
                           ((unsigned)__half_as_ushort(__float2half(e_att[e])) << 16);
            if (p < CAP) payload[(size_t)d * CAP + p] = pay;
            else { int oi = atomicAdd(ovf_count, 1); if (oi < OVF_CAP) ovf_list[oi] = e; }
        }
    }
}

// ---------------- gather: 2 dst rows per wave ----------------
__global__ void __launch_bounds__(256)
gather2_kernel(const __half* __restrict__ emb_h,
               const unsigned* __restrict__ payload,
               const int* __restrict__ cursor,
               const int* __restrict__ dst_idx, const int* __restrict__ src_idx,
               const float* __restrict__ e_att, const float* __restrict__ src_emb,
               const int* __restrict__ ovf_count, const int* __restrict__ ovf_list,
               float* __restrict__ out, int n_dst, int n_src, int rpx) {
    int x    = blockIdx.x & (NPART - 1);
    int g    = blockIdx.x >> 3;
    int wv   = threadIdx.x >> 6;            // wave in block (0..3)
    int lane = threadIdx.x & 63;
    int sub  = lane >> 5;                   // 0/1: which of the wave's 2 rows
    int l31  = lane & 31;                   // column pair owner

    int local = (g * 4 + wv) * 2 + sub;     // row within partition
    int w = x * rpx + local;
    bool rowvalid = (local < rpx) && (w < n_dst);

    int cn = rowvalid ? cursor[w] : 0;
    int cnt = min(cn, CAP);

    // preload my row's payload: lane l31 holds slots {2*l31, 2*l31+1}
    uint2 pp = make_uint2(0u, 0u);
    if (rowvalid) pp = ((const uint2*)(payload + (size_t)w * CAP))[l31];

    // wave-uniform loop bound: max of the two rows' counts
    int cmax = max(cnt, __shfl_xor(cnt, 32));

    float2 acc = make_float2(0.f, 0.f);
    unsigned smax = (unsigned)(n_src - 1);
    for (int j = 0; j < cmax; j += 4) {
        int sl = (sub << 5) | (j >> 1);     // lane holding slots {j, j+1} of my row
        unsigned pv0 = (unsigned)__shfl((int)pp.x, sl);
        unsigned pv1 = (unsigned)__shfl((int)pp.y, sl);
        unsigned pv2 = (unsigned)__shfl((int)pp.x, sl + 1);
        unsigned pv3 = (unsigned)__shfl((int)pp.y, sl + 1);
        float a0 = (j     < cnt) ? __half2float(__ushort_as_half((unsigned short)(pv0 >> 16))) : 0.f;
        float a1 = (j + 1 < cnt) ? __half2float(__ushort_as_half((unsigned short)(pv1 >> 16))) : 0.f;
        float a2 = (j + 2 < cnt) ? __half2float(__ushort_as_half((unsigned short)(pv2 >> 16))) : 0.f;
        float a3 = (j + 3 < cnt) ? __half2float(__ushort_as_half((unsigned short)(pv3 >> 16))) : 0.f;
        unsigned s0 = min(pv0 & 0xffffu, smax);
        unsigned s1 = min(pv1 & 0xffffu, smax);
        unsigned s2 = min(pv2 & 0xffffu, smax);
        unsigned s3 = min(pv3 & 0xffffu, smax);
        // 4 independent 4B half2 loads in flight (wave instr = 256B over 2 rows)
        __half2 h0 = ((const __half2*)(emb_h + (size_t)s0 * D))[l31];
        __half2 h1 = ((const __half2*)(emb_h + (size_t)s1 * D))[l31];
        __half2 h2 = ((const __half2*)(emb_h + (size_t)s2 * D))[l31];
        __half2 h3 = ((const __half2*)(emb_h + (size_t)s3 * D))[l31];
        acc.x = fmaf(__low2float(h0),  a0, acc.x);
        acc.y = fmaf(__high2float(h0), a0, acc.y);
        acc.x = fmaf(__low2float(h1),  a1, acc.x);
        acc.y = fmaf(__high2float(h1), a1, acc.y);
        acc.x = fmaf(__low2float(h2),  a2, acc.x);
        acc.y = fmaf(__high2float(h2), a2, acc.y);
        acc.x = fmaf(__low2float(h3),  a3, acc.x);
        acc.y = fmaf(__high2float(h3), a3, acc.y);
    }

    if (rowvalid) {
        // insurance: bucket overflow (expected never). Exact f32 path.
        if (cn > CAP) {
            int oc = *ovf_count;
            if (oc > OVF_CAP) oc = OVF_CAP;
            for (int i = 0; i < oc; ++i) {
                int e = ovf_list[i];
                if (dst_idx[e] == w) {
                    float a = e_att[e];
                    int   s = src_idx[e];
                    acc.x = fmaf(src_emb[(size_t)s * D + 2 * l31],     a, acc.x);
                    acc.y = fmaf(src_emb[(size_t)s * D + 2 * l31 + 1], a, acc.y);
                }
            }
        }
        ((float2*)(out + (size_t)w * D))[l31] = acc;   // wave store: 512B over 2 rows
    }
}

// ---------------- fallback: pure atomic ----------------
__global__ void __launch_bounds__(256)
atomic_fallback_kernel(const float* __restrict__ src_emb, const float* __restrict__ e_att,
                       const int* __restrict__ src_idx, const int* __restrict__ dst_idx,
                       float* __restrict__ out, int E) {
    int tid  = blockIdx.x * blockDim.x + threadIdx.x;
    int e    = tid >> 4;
    int part = tid & 15;
    if (e >= E) return;
    int   s = src_idx[e];
    int   d = dst_idx[e];
    float a = e_att[e];
    float4 v = ((const float4*)src_emb)[(size_t)s * 16 + part];
    float* orow = out + (size_t)d * D + part * 4;
    atomicAdd(orow + 0, v.x * a);
    atomicAdd(orow + 1, v.y * a);
    atomicAdd(orow + 2, v.z * a);
    atomicAdd(orow + 3, v.w * a);
}

extern "C" void kernel_launch(void* const* d_in, const int* in_sizes, int n_in,
                              void* d_out, int out_size, void* d_ws, size_t ws_size,
                              hipStream_t stream) {
    const float* src_emb = (const float*)d_in[0];
    const float* e_att   = (const float*)d_in[1];
    const int*   src_idx = (const int*)d_in[2];
    const int*   dst_idx = (const int*)d_in[3];
    float*       out     = (float*)d_out;

    const int E     = in_sizes[2];       // 800000
    const int n_dst = out_size / D;      // 50000
    const int n_src = in_sizes[0] / D;   // 50000

    // ws layout (4B units): emb_h[n_src*D/2] | payload[n_dst*CAP] | cursor[n_dst]
    //                       | ovf_count[1] | ovf_list[OVF_CAP]
    size_t off_emb = 0;
    size_t off_pay = off_emb + (size_t)n_src * D / 2;
    size_t off_cur = off_pay + (size_t)n_dst * CAP;
    size_t need_ints = off_cur + (size_t)n_dst + 1 + OVF_CAP;

    if (n_src <= 65536 && ws_size >= need_ints * sizeof(int)) {
        __half*   emb_h   = (__half*)d_ws;
        unsigned* payload = (unsigned*)d_ws + off_pay;
        int*      cursor  = (int*)d_ws + off_cur;
        int*      ovf_count = cursor + n_dst;
        int*      ovf_list  = ovf_count + 1;

        const int n4 = n_src * D / 4;
        convert_emb_kernel<<<(n4 + 255) / 256, 256, 0, stream>>>(
            src_emb, emb_h, n4, cursor, n_dst + 1);

        const int rpx = (n_dst + NPART - 1) / NPART;   // 6250 dst rows/partition
        const int chunks = 512;
        const int E4 = E >> 2;
        const int epb4 = (E4 + chunks - 1) / chunks;
        scatter_xcd_kernel<<<chunks * NPART, 256, 0, stream>>>(
            dst_idx, src_idx, e_att, cursor, payload, ovf_count, ovf_list,
            E, n_dst, rpx, epb4);

        const int gpb = (rpx + 7) / 8;                 // 8 rows per block (4 waves x 2)
        gather2_kernel<<<gpb * NPART, 256, 0, stream>>>(
            emb_h, payload, cursor, dst_idx, src_idx, e_att, src_emb,
            ovf_count, ovf_list, out, n_dst, n_src, rpx);
        return;
    }

    // fallback: pure atomic
    hipMemsetAsync(d_out, 0, (size_t)out_size * sizeof(float), stream);
    atomic_fallback_kernel<<<(E * 16 + 255) / 256, 256, 0, stream>>>(
        src_emb, e_att, src_idx, dst_idx, out, E);
}

// Round 11
// 130.419 us; speedup vs baseline: 1.1276x; 1.0055x over previous
//
#include <hip/hip_runtime.h>
#include <hip/hip_fp16.h>

// msg[e] = src_emb[src_idx[e]] * e_att[e]; out = segment_sum(msg, dst_idx, N_DST)
// src_emb [50000,64] f32, e_att [800000,1] f32, src_idx/dst_idx [800000] i32,
// out [50000,64] f32.
//
// R11 = R10 with:
//  (1) scatter scan loads src4/att4 only when one of the 4 dsts matches the
//      partition (cuts ~30MB of the 8x rescan traffic),
//  (2) convert f32->f16 fused into the scatter kernel's grid (overlaps),
//      cursor zeroing via small memset,
//  (3) gather preloads 32 payload slots (1 dword/lane; P(cnt>32)~3e-4,
//      rare slow path reads the remaining slots directly).
// Scatter is XCD-partitioned (blockIdx&7 = partition; bucket region 1.6MB,
// L2-resident on owning XCD). Gather: 2 dst rows/wave, __half2 4B/lane loads.

#define D 64
#define CAP 64              // slots per dst bucket; deg ~ Binom(E,1/N), max ~45
#define OVF_CAP 65536
#define NPART 8

// ---------------- fused scatter + convert ----------------
__global__ void __launch_bounds__(256)
scatter_conv_kernel(const int* __restrict__ dst_idx, const int* __restrict__ src_idx,
                    const float* __restrict__ e_att, int* __restrict__ cursor,
                    unsigned* __restrict__ payload,
                    int* __restrict__ ovf_count, int* __restrict__ ovf_list,
                    const float* __restrict__ src_emb, __half* __restrict__ emb_h,
                    int E, int n_dst, int rpx, int epb4, int SB, int n4) {
    if ((int)blockIdx.x >= SB) {
        // ---- convert role: f32 -> f16, 4 elems/thread
        int i = ((int)blockIdx.x - SB) * 256 + threadIdx.x;
        if (i < n4) {
            float4 v = ((const float4*)src_emb)[i];
            ushort4 h;
            h.x = __half_as_ushort(__float2half(v.x));
            h.y = __half_as_ushort(__float2half(v.y));
            h.z = __half_as_ushort(__float2half(v.z));
            h.w = __half_as_ushort(__float2half(v.w));
            ((ushort4*)emb_h)[i] = h;
        }
        return;
    }

    // ---- scatter role
    int x     = blockIdx.x & (NPART - 1);   // dst partition == target XCD
    int chunk = blockIdx.x >> 3;
    int lo  = x * rpx;
    int hi  = min(lo + rpx, n_dst);
    unsigned span = (unsigned)(hi - lo);

    int E4 = E >> 2;
    int i0 = chunk * epb4;
    int i1 = min(i0 + epb4, E4);

    for (int i = i0 + threadIdx.x; i < i1; i += 256) {
        int4 d4 = ((const int4*)dst_idx)[i];
        bool m0 = (unsigned)(d4.x - lo) < span;
        bool m1 = (unsigned)(d4.y - lo) < span;
        bool m2 = (unsigned)(d4.z - lo) < span;
        bool m3 = (unsigned)(d4.w - lo) < span;
        if (!(m0 | m1 | m2 | m3)) continue;     // skip src/att loads entirely
        int4   s4 = ((const int4*)src_idx)[i];
        float4 a4 = ((const float4*)e_att)[i];
        int   dd[4] = {d4.x, d4.y, d4.z, d4.w};
        int   ss[4] = {s4.x, s4.y, s4.z, s4.w};
        float aa[4] = {a4.x, a4.y, a4.z, a4.w};
        bool  mm[4] = {m0, m1, m2, m3};
#pragma unroll
        for (int k = 0; k < 4; ++k) {
            if (!mm[k]) continue;
            int d = dd[k];
            int p = atomicAdd(&cursor[d], 1);
            unsigned pay = (unsigned)ss[k] |
                           ((unsigned)__half_as_ushort(__float2half(aa[k])) << 16);
            if (p < CAP) {
                payload[(size_t)d * CAP + p] = pay;   // L2-local on owning XCD
            } else {
                int oi = atomicAdd(ovf_count, 1);
                if (oi < OVF_CAP) ovf_list[oi] = 4 * i + k;
            }
        }
    }
    // tail (E % 4 edges): chunk 0 of every partition, scalar
    if (chunk == 0) {
        for (int e = (E4 << 2) + threadIdx.x; e < E; e += 256) {
            int d = dst_idx[e];
            if ((unsigned)(d - lo) >= span) continue;
            int p = atomicAdd(&cursor[d], 1);
            unsigned pay = (unsigned)src_idx[e] |
                           ((unsigned)__half_as_ushort(__float2half(e_att[e])) << 16);
            if (p < CAP) payload[(size_t)d * CAP + p] = pay;
            else { int oi = atomicAdd(ovf_count, 1); if (oi < OVF_CAP) ovf_list[oi] = e; }
        }
    }
}

// ---------------- gather: 2 dst rows per wave, 32-slot preload ----------------
__global__ void __launch_bounds__(256)
gather2_kernel(const __half* __restrict__ emb_h,
               const unsigned* __restrict__ payload,
               const int* __restrict__ cursor,
               const int* __restrict__ dst_idx, const int* __restrict__ src_idx,
               const float* __restrict__ e_att, const float* __restrict__ src_emb,
               const int* __restrict__ ovf_count, const int* __restrict__ ovf_list,
               float* __restrict__ out, int n_dst, int n_src, int rpx) {
    int x    = blockIdx.x & (NPART - 1);
    int g    = blockIdx.x >> 3;
    int wv   = threadIdx.x >> 6;            // wave in block (0..3)
    int lane = threadIdx.x & 63;
    int sub  = lane >> 5;                   // 0/1: which of the wave's 2 rows
    int l31  = lane & 31;                   // column-pair owner

    int local = (g * 4 + wv) * 2 + sub;     // row within partition
    int w = x * rpx + local;
    bool rowvalid = (local < rpx) && (w < n_dst);

    int cn  = rowvalid ? cursor[w] : 0;
    int cnt = min(cn, CAP);
    int c32 = min(cnt, 32);

    // preload slots 0..31 of my row: lane l31 holds slot l31 (1 dword)
    unsigned pp = 0u;
    if (rowvalid) pp = payload[(size_t)w * CAP + l31];

    // wave-uniform loop bound over the two rows
    int cmax = max(c32, __shfl_xor(c32, 32));

    float2 acc = make_float2(0.f, 0.f);
    unsigned smax = (unsigned)(n_src - 1);
    for (int j = 0; j < cmax; j += 4) {
        int sl = (sub << 5) + j;            // lane holding slot j of my row
        unsigned pv0 = (unsigned)__shfl((int)pp, sl);
        unsigned pv1 = (unsigned)__shfl((int)pp, sl + 1);
        unsigned pv2 = (unsigned)__shfl((int)pp, sl + 2);
        unsigned pv3 = (unsigned)__shfl((int)pp, sl + 3);
        float a0 = (j     < c32) ? __half2float(__ushort_as_half((unsigned short)(pv0 >> 16))) : 0.f;
        float a1 = (j + 1 < c32) ? __half2float(__ushort_as_half((unsigned short)(pv1 >> 16))) : 0.f;
        float a2 = (j + 2 < c32) ? __half2float(__ushort_as_half((unsigned short)(pv2 >> 16))) : 0.f;
        float a3 = (j + 3 < c32) ? __half2float(__ushort_as_half((unsigned short)(pv3 >> 16))) : 0.f;
        unsigned s0 = min(pv0 & 0xffffu, smax);
        unsigned s1 = min(pv1 & 0xffffu, smax);
        unsigned s2 = min(pv2 & 0xffffu, smax);
        unsigned s3 = min(pv3 & 0xffffu, smax);
        // 4 independent 4B half2 loads in flight (wave instr = 256B over 2 rows)
        __half2 h0 = ((const __half2*)(emb_h + (size_t)s0 * D))[l31];
        __half2 h1 = ((const __half2*)(emb_h + (size_t)s1 * D))[l31];
        __half2 h2 = ((const __half2*)(emb_h + (size_t)s2 * D))[l31];
        __half2 h3 = ((const __half2*)(emb_h + (size_t)s3 * D))[l31];
        acc.x = fmaf(__low2float(h0),  a0, acc.x);
        acc.y = fmaf(__high2float(h0), a0, acc.y);
        acc.x = fmaf(__low2float(h1),  a1, acc.x);
        acc.y = fmaf(__high2float(h1), a1, acc.y);
        acc.x = fmaf(__low2float(h2),  a2, acc.x);
        acc.y = fmaf(__high2float(h2), a2, acc.y);
        acc.x = fmaf(__low2float(h3),  a3, acc.x);
        acc.y = fmaf(__high2float(h3), a3, acc.y);
    }

    // rare slow path: slots 32..cnt (P ~ 3e-4 per row)
    if (rowvalid & (cnt > 32)) {
        for (int j = 32; j < cnt; ++j) {
            unsigned pv = payload[(size_t)w * CAP + j];     // broadcast load
            float a = __half2float(__ushort_as_half((unsigned short)(pv >> 16)));
            unsigned s = min(pv & 0xffffu, smax);
            __half2 h = ((const __half2*)(emb_h + (size_t)s * D))[l31];
            acc.x = fmaf(__low2float(h),  a, acc.x);
            acc.y = fmaf(__high2float(h), a, acc.y);
        }
    }

    if (rowvalid) {
        // insurance: bucket overflow (expected never). Exact f32 path.
        if (cn > CAP) {
            int oc = *ovf_count;
            if (oc > OVF_CAP) oc = OVF_CAP;
            for (int i = 0; i < oc; ++i) {
                int e = ovf_list[i];
                if (dst_idx[e] == w) {
                    float a = e_att[e];
                    int   s = src_idx[e];
                    acc.x = fmaf(src_emb[(size_t)s * D + 2 * l31],     a, acc.x);
                    acc.y = fmaf(src_emb[(size_t)s * D + 2 * l31 + 1], a, acc.y);
                }
            }
        }
        ((float2*)(out + (size_t)w * D))[l31] = acc;   // wave store: 512B over 2 rows
    }
}

// ---------------- fallback: pure atomic ----------------
__global__ void __launch_bounds__(256)
atomic_fallback_kernel(const float* __restrict__ src_emb, const float* __restrict__ e_att,
                       const int* __restrict__ src_idx, const int* __restrict__ dst_idx,
                       float* __restrict__ out, int E) {
    int tid  = blockIdx.x * blockDim.x + threadIdx.x;
    int e    = tid >> 4;
    int part = tid & 15;
    if (e >= E) return;
    int   s = src_idx[e];
    int   d = dst_idx[e];
    float a = e_att[e];
    float4 v = ((const float4*)src_emb)[(size_t)s * 16 + part];
    float* orow = out + (size_t)d * D + part * 4;
    atomicAdd(orow + 0, v.x * a);
    atomicAdd(orow + 1, v.y * a);
    atomicAdd(orow + 2, v.z * a);
    atomicAdd(orow + 3, v.w * a);
}

extern "C" void kernel_launch(void* const* d_in, const int* in_sizes, int n_in,
                              void* d_out, int out_size, void* d_ws, size_t ws_size,
                              hipStream_t stream) {
    const float* src_emb = (const float*)d_in[0];
    const float* e_att   = (const float*)d_in[1];
    const int*   src_idx = (const int*)d_in[2];
    const int*   dst_idx = (const int*)d_in[3];
    float*       out     = (float*)d_out;

    const int E     = in_sizes[2];       // 800000
    const int n_dst = out_size / D;      // 50000
    const int n_src = in_sizes[0] / D;   // 50000

    // ws layout (4B units): emb_h[n_src*D/2] | payload[n_dst*CAP] | cursor[n_dst]
    //                       | ovf_count[1] | ovf_list[OVF_CAP]
    size_t off_emb = 0;
    size_t off_pay = off_emb + (size_t)n_src * D / 2;
    size_t off_cur = off_pay + (size_t)n_dst * CAP;
    size_t need_ints = off_cur + (size_t)n_dst + 1 + OVF_CAP;

    if (n_src <= 65536 && ws_size >= need_ints * sizeof(int)) {
        __half*   emb_h   = (__half*)d_ws;
        unsigned* payload = (unsigned*)d_ws + off_pay;
        int*      cursor  = (int*)d_ws + off_cur;
        int*      ovf_count = cursor + n_dst;
        int*      ovf_list  = ovf_count + 1;

        // zero cursor + ovf_count (202 KB)
        hipMemsetAsync(cursor, 0, ((size_t)n_dst + 1) * sizeof(int), stream);

        const int rpx = (n_dst + NPART - 1) / NPART;   // 6250 dst rows/partition
        const int chunks = 512;
        const int SB = chunks * NPART;                 // scatter blocks
        const int E4 = E >> 2;
        const int epb4 = (E4 + chunks - 1) / chunks;
        const int n4 = n_src * D / 4;
        const int CB = (n4 + 255) / 256;               // convert blocks

        scatter_conv_kernel<<<SB + CB, 256, 0, stream>>>(
            dst_idx, src_idx, e_att, cursor, payload, ovf_count, ovf_list,
            src_emb, emb_h, E, n_dst, rpx, epb4, SB, n4);

        const int gpb = (rpx + 7) / 8;                 // 8 rows per block (4 waves x 2)
        gather2_kernel<<<gpb * NPART, 256, 0, stream>>>(
            emb_h, payload, cursor, dst_idx, src_idx, e_att, src_emb,
            ovf_count, ovf_list, out, n_dst, n_src, rpx);
        return;
    }

    // fallback: pure atomic
    hipMemsetAsync(d_out, 0, (size_t)out_size * sizeof(float), stream);
    atomic_fallback_kernel<<<(E * 16 + 255) / 256, 256, 0, stream>>>(
        src_emb, e_att, src_idx, dst_idx, out, E);
}